// Round 8
// baseline (178.699 us; speedup 1.0000x reference)
//
#include <hip/hip_runtime.h>
#include <cstdint>
#include <cstddef>

typedef unsigned short u16;
typedef unsigned int u32;
typedef __bf16 bf16x8 __attribute__((ext_vector_type(8)));
typedef float f32x4 __attribute__((ext_vector_type(4)));
typedef u16 u16x8 __attribute__((ext_vector_type(8)));
typedef u16 u16x4 __attribute__((ext_vector_type(4)));

#define DD 1024
#define HH 16
#define HDIM 64
#define BB 2
#define SS 2048
#define MM (BB * SS)
#define NQT 32  /* 64-row Q tiles */

__device__ __forceinline__ u16 cvt(float f) {
  __bf16 h = (__bf16)f;            // hw round-to-nearest-even on gfx950
  return __builtin_bit_cast(u16, h);
}
__device__ __forceinline__ f32x4 mfma16(bf16x8 a, bf16x8 b, f32x4 c) {
  return __builtin_amdgcn_mfma_f32_16x16x32_bf16(a, b, c, 0, 0, 0);
}
__device__ __forceinline__ bf16x8 ld_bf8(const u16* p) {
  return __builtin_bit_cast(bf16x8, *(const u16x8*)p);
}
// async global->LDS DMA, 16B per lane. LDS dst must be wave-uniform base + lane*16.
__device__ __forceinline__ void async16(const void* g, void* l) {
  __builtin_amdgcn_global_load_lds(
      (__attribute__((address_space(1))) void*)(uintptr_t)g,
      (__attribute__((address_space(3))) void*)l, 16, 0, 0);
}

// ---------------- fused cast fp32 -> bf16 (x + 4 weights, one launch) ----------------
__global__ void cast_all(const float* __restrict__ x, const float* __restrict__ wq,
                         const float* __restrict__ wk, const float* __restrict__ wv,
                         const float* __restrict__ wo, u16* __restrict__ xb,
                         u16* __restrict__ wqb, u16* __restrict__ wkb,
                         u16* __restrict__ wvb, u16* __restrict__ wob) {
  int i = blockIdx.x * 256 + threadIdx.x;   // [0, 2M) float4 units
  const float* src;
  u16* dst;
  int off;
  if (i < (1 << 20)) {
    src = x; dst = xb; off = i;
  } else {
    int j = i - (1 << 20);
    int w = j >> 18;
    off = j & ((1 << 18) - 1);
    src = (w == 0) ? wq : (w == 1) ? wk : (w == 2) ? wv : wo;
    dst = (w == 0) ? wqb : (w == 1) ? wkb : (w == 2) ? wvb : wob;
  }
  float4 v = ((const float4*)src)[off];
  u16x4 o;
  o[0] = cvt(v.x); o[1] = cvt(v.y); o[2] = cvt(v.z); o[3] = cvt(v.w);
  *(u16x4*)&dst[(size_t)off * 4] = o;
}

// ---------------- QKV GEMM + fused RoPE: C[m][e] = sum_k x[m][k] * w[e][k] ----------------
// Q,K out: (B,H,S,HD) bf16, RoPE applied (Q pre-scaled by log2(e)/8);
// V out: TRANSPOSED (B,H,HD,S) bf16
__global__ __launch_bounds__(256) void gemm_qkv(
    const u16* __restrict__ xb, const u16* __restrict__ wq,
    const u16* __restrict__ wk, const u16* __restrict__ wv,
    u16* __restrict__ Qo, u16* __restrict__ Ko, u16* __restrict__ Vto) {
  __shared__ __align__(16) u16 As[128 * 32];
  __shared__ __align__(16) u16 Bs[128 * 32];
  const int t = threadIdx.x;
  const int w = t >> 6, l = t & 63, lane16 = l & 15, quad = l >> 4;
  const int m0 = blockIdx.x * 128, n0 = blockIdx.y * 128;
  const u16* wsel = (blockIdx.z == 0) ? wq : (blockIdx.z == 1) ? wk : wv;
  const int m_w = (w >> 1) * 64, n_w = (w & 1) * 64;
  const int srow = t >> 2, scol = (t & 3) * 8;

  f32x4 acc[4][4] = {};
  for (int kt = 0; kt < 32; ++kt) {
    const int k0 = kt * 32;
    async16(&xb[(size_t)(m0 + srow) * DD + k0 + scol], &As[t * 8]);
    async16(&xb[(size_t)(m0 + 64 + srow) * DD + k0 + scol], &As[2048 + t * 8]);
    async16(&wsel[(size_t)(n0 + srow) * DD + k0 + scol], &Bs[t * 8]);
    async16(&wsel[(size_t)(n0 + 64 + srow) * DD + k0 + scol], &Bs[2048 + t * 8]);
    __syncthreads();
    bf16x8 af[4], bfr[4];
#pragma unroll
    for (int mi = 0; mi < 4; ++mi)
      af[mi] = ld_bf8(&As[(m_w + mi * 16 + lane16) * 32 + quad * 8]);
#pragma unroll
    for (int ni = 0; ni < 4; ++ni)
      bfr[ni] = ld_bf8(&Bs[(n_w + ni * 16 + lane16) * 32 + quad * 8]);
#pragma unroll
    for (int mi = 0; mi < 4; ++mi)
#pragma unroll
      for (int ni = 0; ni < 4; ++ni)
        acc[mi][ni] = mfma16(af[mi], bfr[ni], acc[mi][ni]);
    __syncthreads();
  }
  if (blockIdx.z == 2) {
    // V^T epilogue: the 4 acc regs are 4 consecutive s -> one u16x4 store per (mi,ni)
#pragma unroll
    for (int mi = 0; mi < 4; ++mi) {
      int mbase = m0 + m_w + mi * 16 + quad * 4;
      int b = mbase >> 11, s0 = mbase & (SS - 1);
#pragma unroll
      for (int ni = 0; ni < 4; ++ni) {
        int e = n0 + n_w + ni * 16 + lane16;
        int h = e >> 6, d = e & 63;
        u16x4 pk;
#pragma unroll
        for (int r = 0; r < 4; ++r) pk[r] = cvt(acc[mi][ni][r]);
        *(u16x4*)&Vto[((size_t)(b * HH + h) * HDIM + d) * SS + s0] = pk;
      }
    }
  } else {
    // fused RoPE epilogue: rotate (d, d+32) pairs on fp32 accumulators.
    u16* osel = (blockIdx.z == 0) ? Qo : Ko;
    const float scale = (blockIdx.z == 0) ? 0.18033688f : 1.0f;  // Q: (1/8)*log2(e)
    float invf[2];
    invf[0] = exp2f((float)lane16 * -0.4152410119f) * 0.15915494309f;        // /(2pi)
    invf[1] = exp2f((float)(16 + lane16) * -0.4152410119f) * 0.15915494309f;
    const int h = (n0 + n_w) >> 6;
#pragma unroll
    for (int mi = 0; mi < 4; ++mi) {
#pragma unroll
      for (int r = 0; r < 4; ++r) {
        int mrow = m0 + m_w + mi * 16 + quad * 4 + r;
        int b = mrow >> 11, s = mrow & (SS - 1);
        size_t rowbase = ((size_t)(b * HH + h) * SS + s) * HDIM;
#pragma unroll
        for (int ni = 0; ni < 2; ++ni) {
          float x1 = acc[mi][ni][r], x2 = acc[mi][ni + 2][r];
          float rv = (float)s * invf[ni];
          rv = rv - floorf(rv);                       // revolutions in [0,1)
          float sn = __builtin_amdgcn_sinf(rv);
          float c  = __builtin_amdgcn_cosf(rv);
          int d = ni * 16 + lane16;
          osel[rowbase + d]      = cvt((x1 * c - x2 * sn) * scale);
          osel[rowbase + d + 32] = cvt((x2 * c + x1 * sn) * scale);
        }
      }
    }
  }
}

// ---------------- Flash attention (causal), transposed-S scheme, KV-128 ----------------
// Q,K: (B*H, S, 64) bf16 (RoPE'd, Q scaled by log2e/8) ; Vt: (B*H, 64, S) bf16
// AO: (B, S, H*64) bf16
// Grid: x = bh (32), y -> jj = 31 - y (LPT). Wave = 16 Q-rows x 128 KV-cols.
// S^T = K.Q^T (C: col=q=lane16, row=kv=quad*4+reg)  ->  p = exp2(sc)
// -> P staged per-wave in a 16x64 XOR-swizzled buffer (two kv-64 halves)
// -> O^T = V^T.P ; l = ones.P (MFMA row-sum). LDS exactly 40960 B -> 4 blocks/CU.
__global__ __launch_bounds__(256, 4) void attn_k(const u16* __restrict__ Qb,
                                                 const u16* __restrict__ Kb,
                                                 const u16* __restrict__ Vt,
                                                 u16* __restrict__ AO) {
  __shared__ __align__(16) u16 KsF[128 * 64];    // 16 KB; chunk p: r=p>>3, gc=(p&7)^(r&7)
  __shared__ __align__(16) u16 VtL[64 * 128];    // 16 KB; chunk p: d=p>>4, gq=(p&15)^(d&15)
  __shared__ __align__(16) u16 Ps[4][16 * 64];   // 8 KB; per-wave P half, chunk c^(q&7)
  const int t = threadIdx.x;
  const int w = t >> 6, l = t & 63, lane16 = l & 15, quad = l >> 4;
  const int bh = blockIdx.x;
  const int jj = NQT - 1 - (int)blockIdx.y;
  const size_t base = (size_t)bh * SS * HDIM;
  const u16* Qp = Qb + base;
  const int b = bh >> 4, h = bh & 15;

  const int q0 = jj * 64;
  const int qrow = q0 + w * 16 + lane16;
  bf16x8 qf0 = ld_bf8(&Qp[(size_t)qrow * 64 + quad * 8]);
  bf16x8 qf1 = ld_bf8(&Qp[(size_t)qrow * 64 + 32 + quad * 8]);

  // all-ones A fragment (bf16 1.0 = 0x3F80)
  u16x8 onesu;
#pragma unroll
  for (int i = 0; i < 8; ++i) onesu[i] = 0x3F80;
  const bf16x8 ones = __builtin_bit_cast(bf16x8, onesu);

  f32x4 o[4] = {};    // O^T tiles: col=q=lane16, rows d = nd*16 + quad*4 + r
  f32x4 lacc = {};    // every reg = l[q=lane16]

  // hoisted DMA source pointers (K advances 128*64 elems/iter, V^T 128 elems/iter)
  const u16* kptr[4];
  const u16* vptr[4];
#pragma unroll
  for (int i = 0; i < 4; ++i) {
    int p = i * 256 + t;
    int r = p >> 3;
    int c = (p & 7) ^ (r & 7);
    kptr[i] = Kb + base + (size_t)r * 64 + c * 8;
    int d = p >> 4;
    int q = (p & 15) ^ (d & 15);
    vptr[i] = Vt + base + (size_t)d * SS + q * 8;
  }

  u16* Pw = Ps[w];
  const int ktmax = jj >> 1;
  for (int kt = 0; kt <= ktmax; ++kt) {
    const int kv0 = kt * 128;
    // ---- stage K + V^T via DMA (16B chunks, LDS linear, global swizzled) ----
#pragma unroll
    for (int i = 0; i < 4; ++i) {
      async16(kptr[i], &KsF[(i * 256 + t) * 8]);
      kptr[i] += 128 * 64;
    }
#pragma unroll
    for (int i = 0; i < 4; ++i) {
      async16(vptr[i], &VtL[(i * 256 + t) * 8]);
      vptr[i] += 128;
    }
    __syncthreads();
    // ---- S^T = K Q^T over 128 kv rows (per-lane col q = qrow) ----
    f32x4 st[8];
#pragma unroll
    for (int nc = 0; nc < 8; ++nc) {
      int rr = nc * 16 + lane16;
      int p0 = rr * 8 + (quad ^ (rr & 7));
      int p1 = rr * 8 + ((4 + quad) ^ (rr & 7));
      f32x4 a = {0.f, 0.f, 0.f, 0.f};
      a = mfma16(ld_bf8(&KsF[p0 * 8]), qf0, a);
      a = mfma16(ld_bf8(&KsF[p1 * 8]), qf1, a);
      st[nc] = a;
    }
    // ---- causal mask on last iteration (kv on C rows, q on lanes) ----
    if (kt == ktmax) {
#pragma unroll
      for (int nc = 0; nc < 8; ++nc) {
        int kvb = kv0 + nc * 16 + quad * 4;
#pragma unroll
        for (int r = 0; r < 4; ++r)
          if (kvb + r > qrow) st[nc][r] = -3.0e38f;
      }
    }
    // ---- softmax numerator: p = 2^sc (bias cancels in normalization) ----
#pragma unroll
    for (int nc = 0; nc < 8; ++nc)
#pragma unroll
      for (int r = 0; r < 4; ++r) st[nc][r] = exp2f(st[nc][r]);
    // ---- per kv-64 half: P -> per-wave swizzled LDS (b64 writes) -> B-frags -> PV ----
#pragma unroll
    for (int kh = 0; kh < 2; ++kh) {
      // write: 4 consecutive kv per lane at row q=lane16
#pragma unroll
      for (int ncr = 0; ncr < 4; ++ncr) {
        f32x4 v = st[kh * 4 + ncr];
        u16x4 pk;
#pragma unroll
        for (int r = 0; r < 4; ++r) pk[r] = cvt(v[r]);
        int addr = lane16 * 64 + (((ncr * 2 + (quad >> 1)) ^ (lane16 & 7)) * 8) +
                   (quad & 1) * 4;
        *(u16x4*)&Pw[addr] = pk;
      }
      // read B-frags (K=32 each) and accumulate O^T, l
#pragma unroll
      for (int cf = 0; cf < 2; ++cf) {
        bf16x8 pf = ld_bf8(&Pw[lane16 * 64 + (((cf * 4 + quad) ^ (lane16 & 7)) * 8)]);
        lacc = mfma16(ones, pf, lacc);
        int g = kh * 8 + cf * 4 + quad;        // global kv chunk within the 128-tile
#pragma unroll
        for (int nd = 0; nd < 4; ++nd) {
          int d = nd * 16 + lane16;
          bf16x8 bv = ld_bf8(&VtL[(size_t)d * 128 + ((g ^ lane16) * 8)]);
          o[nd] = mfma16(bv, pf, o[nd]);
        }
      }
    }
    __syncthreads();
  }
  // ---- epilogue: O^T col q=lane16; d = nd*16 + quad*4 + r (u16x4 stores) ----
  const float inv = 1.0f / lacc[0];
  const size_t rowb = (size_t)(b * SS + qrow) * DD + h * HDIM + quad * 4;
#pragma unroll
  for (int nd = 0; nd < 4; ++nd) {
    u16x4 pk;
#pragma unroll
    for (int r = 0; r < 4; ++r) pk[r] = cvt(o[nd][r] * inv);
    *(u16x4*)&AO[rowb + nd * 16] = pk;
  }
}

// ---------------- output GEMM: out[m][e] = sum_k AO[m][k] * wo[e][k] (fp32 out) ----------------
__global__ __launch_bounds__(256) void gemm_out(const u16* __restrict__ A, const u16* __restrict__ W,
                                                float* __restrict__ out) {
  __shared__ __align__(16) u16 As[128 * 32];
  __shared__ __align__(16) u16 Bs[128 * 32];
  const int t = threadIdx.x;
  const int w = t >> 6, l = t & 63, lane16 = l & 15, quad = l >> 4;
  const int m0 = blockIdx.x * 128, n0 = blockIdx.y * 128;
  const int m_w = (w >> 1) * 64, n_w = (w & 1) * 64;
  const int srow = t >> 2, scol = (t & 3) * 8;

  f32x4 acc[4][4] = {};
  for (int kt = 0; kt < 32; ++kt) {
    const int k0 = kt * 32;
    async16(&A[(size_t)(m0 + srow) * DD + k0 + scol], &As[t * 8]);
    async16(&A[(size_t)(m0 + 64 + srow) * DD + k0 + scol], &As[2048 + t * 8]);
    async16(&W[(size_t)(n0 + srow) * DD + k0 + scol], &Bs[t * 8]);
    async16(&W[(size_t)(n0 + 64 + srow) * DD + k0 + scol], &Bs[2048 + t * 8]);
    __syncthreads();
    bf16x8 af[4], bfr[4];
#pragma unroll
    for (int mi = 0; mi < 4; ++mi)
      af[mi] = ld_bf8(&As[(m_w + mi * 16 + lane16) * 32 + quad * 8]);
#pragma unroll
    for (int ni = 0; ni < 4; ++ni)
      bfr[ni] = ld_bf8(&Bs[(n_w + ni * 16 + lane16) * 32 + quad * 8]);
#pragma unroll
    for (int mi = 0; mi < 4; ++mi)
#pragma unroll
      for (int ni = 0; ni < 4; ++ni)
        acc[mi][ni] = mfma16(af[mi], bfr[ni], acc[mi][ni]);
    __syncthreads();
  }
#pragma unroll
  for (int mi = 0; mi < 4; ++mi) {
#pragma unroll
    for (int r = 0; r < 4; ++r) {
      int mrow = m0 + m_w + mi * 16 + quad * 4 + r;
#pragma unroll
      for (int ni = 0; ni < 4; ++ni) {
        int e = n0 + n_w + ni * 16 + lane16;
        out[(size_t)mrow * DD + e] = acc[mi][ni][r];
      }
    }
  }
}

extern "C" void kernel_launch(void* const* d_in, const int* in_sizes, int n_in,
                              void* d_out, int out_size, void* d_ws, size_t ws_size,
                              hipStream_t stream) {
  const float* x  = (const float*)d_in[0];
  const float* wq = (const float*)d_in[1];
  const float* wk = (const float*)d_in[2];
  const float* wv = (const float*)d_in[3];
  const float* wo = (const float*)d_in[4];
  float* out = (float*)d_out;
  char* ws = (char*)d_ws;

  u16* xb  = (u16*)(ws + (size_t)0);
  u16* wqb = (u16*)(ws + ((size_t)8  << 20));
  u16* wkb = (u16*)(ws + ((size_t)10 << 20));
  u16* wvb = (u16*)(ws + ((size_t)12 << 20));
  u16* wob = (u16*)(ws + ((size_t)14 << 20));
  u16* Qb  = (u16*)(ws + ((size_t)16 << 20));
  u16* Kb  = (u16*)(ws + ((size_t)24 << 20));
  u16* Vtg = (u16*)(ws + ((size_t)32 << 20));
  u16* AO  = (u16*)(ws + ((size_t)40 << 20));

  cast_all<<<8192, 256, 0, stream>>>(x, wq, wk, wv, wo, xb, wqb, wkb, wvb, wob);
  gemm_qkv<<<dim3(32, 8, 3), 256, 0, stream>>>(xb, wqb, wkb, wvb, Qb, Kb, Vtg);
  attn_k<<<dim3(32, 32), 256, 0, stream>>>(Qb, Kb, Vtg, AO);
  gemm_out<<<dim3(32, 8), 256, 0, stream>>>(AO, wob, out);
}

// Round 9
// 168.452 us; speedup vs baseline: 1.0608x; 1.0608x over previous
//
#include <hip/hip_runtime.h>
#include <cstdint>
#include <cstddef>

typedef unsigned short u16;
typedef unsigned int u32;
typedef __bf16 bf16x8 __attribute__((ext_vector_type(8)));
typedef float f32x4 __attribute__((ext_vector_type(4)));
typedef u16 u16x8 __attribute__((ext_vector_type(8)));
typedef u16 u16x4 __attribute__((ext_vector_type(4)));

#define DD 1024
#define HH 16
#define HDIM 64
#define BB 2
#define SS 2048
#define MM (BB * SS)
#define NQT 32  /* 64-row Q tiles */

__device__ __forceinline__ u16 cvt(float f) {
  __bf16 h = (__bf16)f;            // hw round-to-nearest-even on gfx950
  return __builtin_bit_cast(u16, h);
}
__device__ __forceinline__ f32x4 mfma16(bf16x8 a, bf16x8 b, f32x4 c) {
  return __builtin_amdgcn_mfma_f32_16x16x32_bf16(a, b, c, 0, 0, 0);
}
__device__ __forceinline__ bf16x8 ld_bf8(const u16* p) {
  return __builtin_bit_cast(bf16x8, *(const u16x8*)p);
}
// async global->LDS DMA, 16B per lane. LDS dst must be wave-uniform base + lane*16.
__device__ __forceinline__ void async16(const void* g, void* l) {
  __builtin_amdgcn_global_load_lds(
      (__attribute__((address_space(1))) void*)(uintptr_t)g,
      (__attribute__((address_space(3))) void*)l, 16, 0, 0);
}

// ---------------- fused cast fp32 -> bf16 (x + 4 weights, one launch) ----------------
__global__ void cast_all(const float* __restrict__ x, const float* __restrict__ wq,
                         const float* __restrict__ wk, const float* __restrict__ wv,
                         const float* __restrict__ wo, u16* __restrict__ xb,
                         u16* __restrict__ wqb, u16* __restrict__ wkb,
                         u16* __restrict__ wvb, u16* __restrict__ wob) {
  int i = blockIdx.x * 256 + threadIdx.x;   // [0, 2M) float4 units
  const float* src;
  u16* dst;
  int off;
  if (i < (1 << 20)) {
    src = x; dst = xb; off = i;
  } else {
    int j = i - (1 << 20);
    int w = j >> 18;
    off = j & ((1 << 18) - 1);
    src = (w == 0) ? wq : (w == 1) ? wk : (w == 2) ? wv : wo;
    dst = (w == 0) ? wqb : (w == 1) ? wkb : (w == 2) ? wvb : wob;
  }
  float4 v = ((const float4*)src)[off];
  u16x4 o;
  o[0] = cvt(v.x); o[1] = cvt(v.y); o[2] = cvt(v.z); o[3] = cvt(v.w);
  *(u16x4*)&dst[(size_t)off * 4] = o;
}

// ---------------- QKV GEMM + fused RoPE: C[m][e] = sum_k x[m][k] * w[e][k] ----------------
// Q,K out: (B,H,S,HD) bf16, RoPE applied (Q pre-scaled by log2(e)/8);
// V out: TRANSPOSED (B,H,HD,S) bf16
__global__ __launch_bounds__(256) void gemm_qkv(
    const u16* __restrict__ xb, const u16* __restrict__ wq,
    const u16* __restrict__ wk, const u16* __restrict__ wv,
    u16* __restrict__ Qo, u16* __restrict__ Ko, u16* __restrict__ Vto) {
  __shared__ __align__(16) u16 As[128 * 32];
  __shared__ __align__(16) u16 Bs[128 * 32];
  const int t = threadIdx.x;
  const int w = t >> 6, l = t & 63, lane16 = l & 15, quad = l >> 4;
  const int m0 = blockIdx.x * 128, n0 = blockIdx.y * 128;
  const u16* wsel = (blockIdx.z == 0) ? wq : (blockIdx.z == 1) ? wk : wv;
  const int m_w = (w >> 1) * 64, n_w = (w & 1) * 64;
  const int srow = t >> 2, scol = (t & 3) * 8;

  f32x4 acc[4][4] = {};
  for (int kt = 0; kt < 32; ++kt) {
    const int k0 = kt * 32;
    async16(&xb[(size_t)(m0 + srow) * DD + k0 + scol], &As[t * 8]);
    async16(&xb[(size_t)(m0 + 64 + srow) * DD + k0 + scol], &As[2048 + t * 8]);
    async16(&wsel[(size_t)(n0 + srow) * DD + k0 + scol], &Bs[t * 8]);
    async16(&wsel[(size_t)(n0 + 64 + srow) * DD + k0 + scol], &Bs[2048 + t * 8]);
    __syncthreads();
    bf16x8 af[4], bfr[4];
#pragma unroll
    for (int mi = 0; mi < 4; ++mi)
      af[mi] = ld_bf8(&As[(m_w + mi * 16 + lane16) * 32 + quad * 8]);
#pragma unroll
    for (int ni = 0; ni < 4; ++ni)
      bfr[ni] = ld_bf8(&Bs[(n_w + ni * 16 + lane16) * 32 + quad * 8]);
#pragma unroll
    for (int mi = 0; mi < 4; ++mi)
#pragma unroll
      for (int ni = 0; ni < 4; ++ni)
        acc[mi][ni] = mfma16(af[mi], bfr[ni], acc[mi][ni]);
    __syncthreads();
  }
  if (blockIdx.z == 2) {
    // V^T epilogue: the 4 acc regs are 4 consecutive s -> one u16x4 store per (mi,ni)
#pragma unroll
    for (int mi = 0; mi < 4; ++mi) {
      int mbase = m0 + m_w + mi * 16 + quad * 4;
      int b = mbase >> 11, s0 = mbase & (SS - 1);
#pragma unroll
      for (int ni = 0; ni < 4; ++ni) {
        int e = n0 + n_w + ni * 16 + lane16;
        int h = e >> 6, d = e & 63;
        u16x4 pk;
#pragma unroll
        for (int r = 0; r < 4; ++r) pk[r] = cvt(acc[mi][ni][r]);
        *(u16x4*)&Vto[((size_t)(b * HH + h) * HDIM + d) * SS + s0] = pk;
      }
    }
  } else {
    // fused RoPE epilogue: rotate (d, d+32) pairs on fp32 accumulators.
    u16* osel = (blockIdx.z == 0) ? Qo : Ko;
    const float scale = (blockIdx.z == 0) ? 0.18033688f : 1.0f;  // Q: (1/8)*log2(e)
    float invf[2];
    invf[0] = exp2f((float)lane16 * -0.4152410119f) * 0.15915494309f;        // /(2pi)
    invf[1] = exp2f((float)(16 + lane16) * -0.4152410119f) * 0.15915494309f;
    const int h = (n0 + n_w) >> 6;
#pragma unroll
    for (int mi = 0; mi < 4; ++mi) {
#pragma unroll
      for (int r = 0; r < 4; ++r) {
        int mrow = m0 + m_w + mi * 16 + quad * 4 + r;
        int b = mrow >> 11, s = mrow & (SS - 1);
        size_t rowbase = ((size_t)(b * HH + h) * SS + s) * HDIM;
#pragma unroll
        for (int ni = 0; ni < 2; ++ni) {
          float x1 = acc[mi][ni][r], x2 = acc[mi][ni + 2][r];
          float rv = (float)s * invf[ni];
          rv = rv - floorf(rv);                       // revolutions in [0,1)
          float sn = __builtin_amdgcn_sinf(rv);
          float c  = __builtin_amdgcn_cosf(rv);
          int d = ni * 16 + lane16;
          osel[rowbase + d]      = cvt((x1 * c - x2 * sn) * scale);
          osel[rowbase + d + 32] = cvt((x2 * c + x1 * sn) * scale);
        }
      }
    }
  }
}

// ---------------- Flash attention (causal), transposed-S, double-buffered async ----------
// Q,K: (B*H, S, 64) bf16 (RoPE'd, Q scaled by log2e/8) ; Vt: (B*H, 64, S) bf16
// AO: (B, S, H*64) bf16
// Grid: x = bh (32), y -> jj = 31 - y (LPT). Wave = 16 Q-rows x 128 KV-cols.
// Pipeline: ONE barrier/iter; DMA for tile i+1 issued after barrier_i, drained at
// barrier_{i+1} (a full compute later) -> staging latency hidden.
// S^T = K.Q^T -> p = exp2(sc) -> Ps (16x128/wave, XOR-swizzled) -> O^T = V^T.P,
// l = ones.P (MFMA row-sum). LDS exactly 80 KB -> 2 blocks/CU.
__global__ __launch_bounds__(256, 2) void attn_k(const u16* __restrict__ Qb,
                                                 const u16* __restrict__ Kb,
                                                 const u16* __restrict__ Vt,
                                                 u16* __restrict__ AO) {
  __shared__ __align__(16) u16 KsF[2][128 * 64]; // 32 KB; chunk p: r=p>>3, gc=(p&7)^(r&7)
  __shared__ __align__(16) u16 VtL[2][64 * 128]; // 32 KB; chunk p: d=p>>4, gq=(p&15)^(d&15)
  __shared__ __align__(16) u16 Ps[4][16 * 128];  // 16 KB; per-wave P, chunk c^(q&15)
  const int t = threadIdx.x;
  const int w = t >> 6, l = t & 63, lane16 = l & 15, quad = l >> 4;
  const int bh = blockIdx.x;
  const int jj = NQT - 1 - (int)blockIdx.y;
  const size_t base = (size_t)bh * SS * HDIM;
  const u16* Qp = Qb + base;
  const int b = bh >> 4, h = bh & 15;

  const int q0 = jj * 64;
  const int qrow = q0 + w * 16 + lane16;
  bf16x8 qf0 = ld_bf8(&Qp[(size_t)qrow * 64 + quad * 8]);
  bf16x8 qf1 = ld_bf8(&Qp[(size_t)qrow * 64 + 32 + quad * 8]);

  // all-ones A fragment (bf16 1.0 = 0x3F80)
  u16x8 onesu;
#pragma unroll
  for (int i = 0; i < 8; ++i) onesu[i] = 0x3F80;
  const bf16x8 ones = __builtin_bit_cast(bf16x8, onesu);

  f32x4 o[4] = {};    // O^T tiles: col=q=lane16, rows d = nd*16 + quad*4 + r
  f32x4 lacc = {};    // every reg = l[q=lane16]

  // DMA source pointers (K advances 128*64 elems/tile, V^T 128 elems/tile)
  const u16* kptr[4];
  const u16* vptr[4];
#pragma unroll
  for (int i = 0; i < 4; ++i) {
    int p = i * 256 + t;
    int r = p >> 3;
    int c = (p & 7) ^ (r & 7);
    kptr[i] = Kb + base + (size_t)r * 64 + c * 8;
    int d = p >> 4;
    int q = (p & 15) ^ (d & 15);
    vptr[i] = Vt + base + (size_t)d * SS + q * 8;
  }

  // ---- prologue: stage tile 0 into buffer 0 ----
#pragma unroll
  for (int i = 0; i < 4; ++i) {
    async16(kptr[i], &KsF[0][(i * 256 + t) * 8]);
    kptr[i] += 128 * 64;
    async16(vptr[i], &VtL[0][(i * 256 + t) * 8]);
    vptr[i] += 128;
  }

  u16* Pw = Ps[w];
  const int ktmax = jj >> 1;
  for (int kt = 0; kt <= ktmax; ++kt) {
    __syncthreads();   // drains tile-kt DMA (issued a full compute ago, except kt=0)
    if (kt < ktmax) {  // prefetch tile kt+1 into the other buffer
      const int nb = (kt + 1) & 1;
#pragma unroll
      for (int i = 0; i < 4; ++i) {
        async16(kptr[i], &KsF[nb][(i * 256 + t) * 8]);
        kptr[i] += 128 * 64;
        async16(vptr[i], &VtL[nb][(i * 256 + t) * 8]);
        vptr[i] += 128;
      }
    }
    const u16* Kc = KsF[kt & 1];
    const u16* Vc = VtL[kt & 1];
    const int kv0 = kt * 128;
    // ---- S^T = K Q^T over 128 kv rows (per-lane col q = qrow) ----
    f32x4 st[8];
#pragma unroll
    for (int nc = 0; nc < 8; ++nc) {
      int rr = nc * 16 + lane16;
      int p0 = rr * 8 + (quad ^ (rr & 7));
      int p1 = rr * 8 + ((4 + quad) ^ (rr & 7));
      f32x4 a = {0.f, 0.f, 0.f, 0.f};
      a = mfma16(ld_bf8(&Kc[p0 * 8]), qf0, a);
      a = mfma16(ld_bf8(&Kc[p1 * 8]), qf1, a);
      st[nc] = a;
    }
    // ---- causal mask on last iteration (kv on C rows, q on lanes) ----
    if (kt == ktmax) {
#pragma unroll
      for (int nc = 0; nc < 8; ++nc) {
        int kvb = kv0 + nc * 16 + quad * 4;
#pragma unroll
        for (int r = 0; r < 4; ++r)
          if (kvb + r > qrow) st[nc][r] = -3.0e38f;
      }
    }
    // ---- softmax numerator: p = 2^sc (bias cancels in normalization) ----
#pragma unroll
    for (int nc = 0; nc < 8; ++nc)
#pragma unroll
      for (int r = 0; r < 4; ++r) st[nc][r] = exp2f(st[nc][r]);
    // ---- P -> per-wave swizzled LDS (8 b64 writes, full 128-kv width) ----
#pragma unroll
    for (int nc = 0; nc < 8; ++nc) {
      u16x4 pk;
#pragma unroll
      for (int r = 0; r < 4; ++r) pk[r] = cvt(st[nc][r]);
      int addr = lane16 * 128 + (((nc * 2 + (quad >> 1)) ^ lane16) * 8) + (quad & 1) * 4;
      *(u16x4*)&Pw[addr] = pk;
    }
    // ---- read 4 B-frags, accumulate O^T and l ----
#pragma unroll
    for (int G = 0; G < 4; ++G) {
      int gc = ((G * 4 + quad) ^ lane16) * 8;
      bf16x8 pf = ld_bf8(&Pw[lane16 * 128 + gc]);
      lacc = mfma16(ones, pf, lacc);
#pragma unroll
      for (int nd = 0; nd < 4; ++nd) {
        int d = nd * 16 + lane16;
        bf16x8 bv = ld_bf8(&Vc[(size_t)d * 128 + gc]);
        o[nd] = mfma16(bv, pf, o[nd]);
      }
    }
  }
  // ---- epilogue: O^T col q=lane16; d = nd*16 + quad*4 + r (u16x4 stores) ----
  const float inv = 1.0f / lacc[0];
  const size_t rowb = (size_t)(b * SS + qrow) * DD + h * HDIM + quad * 4;
#pragma unroll
  for (int nd = 0; nd < 4; ++nd) {
    u16x4 pk;
#pragma unroll
    for (int r = 0; r < 4; ++r) pk[r] = cvt(o[nd][r] * inv);
    *(u16x4*)&AO[rowb + nd * 16] = pk;
  }
}

// ---------------- output GEMM: out[m][e] = sum_k AO[m][k] * wo[e][k] (fp32 out) -------
// 128x64 tiles -> grid 512 (2 blocks/CU; old 128x128 grid 256 was 1 block/CU).
__global__ __launch_bounds__(256) void gemm_out(const u16* __restrict__ A, const u16* __restrict__ W,
                                                float* __restrict__ out) {
  __shared__ __align__(16) u16 As[128 * 32];  // 8 KB
  __shared__ __align__(16) u16 Bs[64 * 32];   // 4 KB
  const int t = threadIdx.x;
  const int w = t >> 6, l = t & 63, lane16 = l & 15, quad = l >> 4;
  const int m0 = blockIdx.x * 128, n0 = blockIdx.y * 64;
  const int m_w = (w >> 1) * 64, n_w = (w & 1) * 32;
  const int srow = t >> 2, scol = (t & 3) * 8;

  f32x4 acc[4][2] = {};
  for (int kt = 0; kt < 32; ++kt) {
    const int k0 = kt * 32;
    async16(&A[(size_t)(m0 + srow) * DD + k0 + scol], &As[t * 8]);
    async16(&A[(size_t)(m0 + 64 + srow) * DD + k0 + scol], &As[2048 + t * 8]);
    async16(&W[(size_t)(n0 + srow) * DD + k0 + scol], &Bs[t * 8]);
    __syncthreads();
    bf16x8 af[4], bfr[2];
#pragma unroll
    for (int mi = 0; mi < 4; ++mi)
      af[mi] = ld_bf8(&As[(m_w + mi * 16 + lane16) * 32 + quad * 8]);
#pragma unroll
    for (int ni = 0; ni < 2; ++ni)
      bfr[ni] = ld_bf8(&Bs[(n_w + ni * 16 + lane16) * 32 + quad * 8]);
#pragma unroll
    for (int mi = 0; mi < 4; ++mi)
#pragma unroll
      for (int ni = 0; ni < 2; ++ni)
        acc[mi][ni] = mfma16(af[mi], bfr[ni], acc[mi][ni]);
    __syncthreads();
  }
#pragma unroll
  for (int mi = 0; mi < 4; ++mi) {
#pragma unroll
    for (int r = 0; r < 4; ++r) {
      int mrow = m0 + m_w + mi * 16 + quad * 4 + r;
#pragma unroll
      for (int ni = 0; ni < 2; ++ni) {
        int e = n0 + n_w + ni * 16 + lane16;
        out[(size_t)mrow * DD + e] = acc[mi][ni][r];
      }
    }
  }
}

extern "C" void kernel_launch(void* const* d_in, const int* in_sizes, int n_in,
                              void* d_out, int out_size, void* d_ws, size_t ws_size,
                              hipStream_t stream) {
  const float* x  = (const float*)d_in[0];
  const float* wq = (const float*)d_in[1];
  const float* wk = (const float*)d_in[2];
  const float* wv = (const float*)d_in[3];
  const float* wo = (const float*)d_in[4];
  float* out = (float*)d_out;
  char* ws = (char*)d_ws;

  u16* xb  = (u16*)(ws + (size_t)0);
  u16* wqb = (u16*)(ws + ((size_t)8  << 20));
  u16* wkb = (u16*)(ws + ((size_t)10 << 20));
  u16* wvb = (u16*)(ws + ((size_t)12 << 20));
  u16* wob = (u16*)(ws + ((size_t)14 << 20));
  u16* Qb  = (u16*)(ws + ((size_t)16 << 20));
  u16* Kb  = (u16*)(ws + ((size_t)24 << 20));
  u16* Vtg = (u16*)(ws + ((size_t)32 << 20));
  u16* AO  = (u16*)(ws + ((size_t)40 << 20));

  cast_all<<<8192, 256, 0, stream>>>(x, wq, wk, wv, wo, xb, wqb, wkb, wvb, wob);
  gemm_qkv<<<dim3(32, 8, 3), 256, 0, stream>>>(xb, wqb, wkb, wvb, Qb, Kb, Vtg);
  attn_k<<<dim3(32, 32), 256, 0, stream>>>(Qb, Kb, Vtg, AO);
  gemm_out<<<dim3(32, 16), 256, 0, stream>>>(AO, wob, out);
}